// Round 6
// baseline (49.828 us; speedup 1.0000x reference)
//
#include <hip/hip_runtime.h>
#include <hip/hip_bf16.h>

typedef __attribute__((ext_vector_type(8))) short bf16x8;
typedef __attribute__((ext_vector_type(4))) float f32x4;

constexpr int BQ  = 4096;          // batch per view
constexpr int DD  = 128;           // dim
constexpr int N2  = 2 * BQ;        // 8192
constexpr int NCHK = 8;            // column chunks (1024 cols each)
constexpr int NCT  = 8;            // 128-col tiles per chunk
// exp(s/T) = exp2(s * 2/ln2); pre-scale matrix by sqrt(2.8853900817779268)
constexpr float SQS = 1.6986433f;

static __device__ __forceinline__ ushort f2bf(float f) {
    unsigned u = __builtin_bit_cast(unsigned, f);
    u += 0x7FFFu + ((u >> 16) & 1u);     // round-to-nearest-even
    return (ushort)(u >> 16);
}

static __device__ __forceinline__ void gll(const void* g, void* l) {
    __builtin_amdgcn_global_load_lds(
        (const __attribute__((address_space(1))) void*)g,
        (__attribute__((address_space(3))) void*)l, 16, 0, 0);
}

// ---- kernel 1: fp32 -> bf16 in MFMA-fragment order -------------------------
// obF layout: frag(group,kk) at index (group*4+kk)*64+lane, 8 bf16 per lane:
// a fragment load is F[base+lane] -> one fully contiguous 1KB load per wave.
__global__ __launch_bounds__(256) void convert_k(const float* __restrict__ a,
        const float* __restrict__ b, ushort* __restrict__ obF)
{
    int t = blockIdx.x * 256 + threadIdx.x;          // 131072 threads
    int row = t >> 4, c8 = t & 15;
    const float* src = (row < BQ) ? (a + (size_t)row * DD + c8 * 8)
                                  : (b + (size_t)(row - BQ) * DD + c8 * 8);
    float4 v0 = reinterpret_cast<const float4*>(src)[0];
    float4 v1 = reinterpret_cast<const float4*>(src)[1];
    bf16x8 res;
    res[0] = (short)f2bf(v0.x * SQS); res[1] = (short)f2bf(v0.y * SQS);
    res[2] = (short)f2bf(v0.z * SQS); res[3] = (short)f2bf(v0.w * SQS);
    res[4] = (short)f2bf(v1.x * SQS); res[5] = (short)f2bf(v1.y * SQS);
    res[6] = (short)f2bf(v1.z * SQS); res[7] = (short)f2bf(v1.w * SQS);
    int frag = ((row >> 4) * 4 + (c8 >> 2)) * 64 + (c8 & 3) * 16 + (row & 15);
    *reinterpret_cast<bf16x8*>(obF + (size_t)frag * 8) = res;
}

// ---- kernel 2: per-target-group exp-Gram row sums ---------------------------
// For t_i != -1 the reference's exclusion set is EXACTLY {j : t_j == t_i}
// (self and the paired column share the target). grpsum(i) = sum over that
// set; Ng = full - grpsum. One block per target value v in [0,100).
// Recomputes the same bf16 values + same MFMA kk-chain as the main kernel,
// so the subtracted terms are bitwise identical to the ones added into full.
__global__ __launch_bounds__(256) void group_k(
        const float* __restrict__ out1, const float* __restrict__ out2,
        const int* __restrict__ tgt, float* __restrict__ grpsum)
{
    __shared__ ushort gfrag[32768];     // 256 rows, fragment order, 64KB
    __shared__ short  glist[256];
    __shared__ int    pc[256];
    __shared__ int    pofs[256];
    __shared__ int    gcs;

    const int tid = threadIdx.x;
    const int v   = blockIdx.x;

    // stable compaction of {p : tgt[p]==v}: count, prefix, re-scan write
    int cnt = 0;
#pragma unroll
    for (int k = 0; k < 16; ++k)
        cnt += (tgt[tid * 16 + k] == v);
    pc[tid] = cnt;
    __syncthreads();
    if (tid < 64) {
        int s0 = pc[tid*4+0], s1 = pc[tid*4+1], s2 = pc[tid*4+2], s3 = pc[tid*4+3];
        int inc = s0 + s1 + s2 + s3;
        int tot = inc;
#pragma unroll
        for (int d = 1; d < 64; d <<= 1) {
            int t = __shfl_up(inc, d);
            if (tid >= d) inc += t;
        }
        int exc = inc - tot;
        pofs[tid*4+0] = exc;
        pofs[tid*4+1] = exc + s0;
        pofs[tid*4+2] = exc + s0 + s1;
        pofs[tid*4+3] = exc + s0 + s1 + s2;
        if (tid == 63) gcs = inc;
    }
    __syncthreads();
    {
        int o = pofs[tid];
        for (int k = 0; k < 16; ++k) {
            int p = tid * 16 + k;
            if (tgt[p] == v) { if (o < 256) glist[o] = (short)p; ++o; }
        }
    }
    __syncthreads();
    const int c  = (gcs < 128) ? gcs : 128;   // pairs (c ~41 expected; 128 = 13 sigma)
    const int c2 = 2 * c;                      // rows in group (both views)

    // stage 2c rows as SQS-prescaled bf16 in fragment order; pad rows = 0
    {
        const int s = tid;
        const bool live = s < c2;
        const float* src = live ? ((s < c) ? out1 + (size_t)glist[s] * DD
                                           : out2 + (size_t)glist[s - c] * DD)
                                : out1;
#pragma unroll
        for (int c8 = 0; c8 < 16; ++c8) {
            bf16x8 res = {};
            if (live) {
                float4 v0 = reinterpret_cast<const float4*>(src + c8 * 8)[0];
                float4 v1 = reinterpret_cast<const float4*>(src + c8 * 8)[1];
                res[0]=(short)f2bf(v0.x*SQS); res[1]=(short)f2bf(v0.y*SQS);
                res[2]=(short)f2bf(v0.z*SQS); res[3]=(short)f2bf(v0.w*SQS);
                res[4]=(short)f2bf(v1.x*SQS); res[5]=(short)f2bf(v1.y*SQS);
                res[6]=(short)f2bf(v1.z*SQS); res[7]=(short)f2bf(v1.w*SQS);
            }
            int frag = ((s >> 4) * 4 + (c8 >> 2)) * 64 + (c8 & 3) * 16 + (s & 15);
            *reinterpret_cast<bf16x8*>(&gfrag[frag * 8]) = res;
        }
    }
    __syncthreads();

    // 256x256 exp-Gram row sums; wave w owns rows w*64..w*64+63
    const int lane = tid & 63;
    const int w    = tid >> 6;
    const int l15  = lane & 15;
    const int l4   = lane >> 4;
    const bf16x8* Fl = reinterpret_cast<const bf16x8*>(gfrag);

    bf16x8 af[4][4];
#pragma unroll
    for (int m = 0; m < 4; ++m)
#pragma unroll
        for (int kk = 0; kk < 4; ++kk)
            af[m][kk] = Fl[((w * 4 + m) * 4 + kk) * 64 + lane];

    float fs[4][4] = {};
#pragma unroll
    for (int ct = 0; ct < 4; ++ct) {
        f32x4 acc[4][4] = {};
#pragma unroll
        for (int kk = 0; kk < 4; ++kk) {
            bf16x8 bf[4];
#pragma unroll
            for (int n = 0; n < 4; ++n)
                bf[n] = Fl[((ct * 4 + n) * 4 + kk) * 64 + lane];
#pragma unroll
            for (int m = 0; m < 4; ++m)
#pragma unroll
                for (int n = 0; n < 4; ++n)
                    acc[m][n] = __builtin_amdgcn_mfma_f32_16x16x32_bf16(
                        af[m][kk], bf[n], acc[m][n], 0, 0, 0);
        }
#pragma unroll
        for (int m = 0; m < 4; ++m)
#pragma unroll
            for (int n = 0; n < 4; ++n) {
                int col = ct * 64 + n * 16 + l15;
#pragma unroll
                for (int r = 0; r < 4; ++r) {
                    float e = __builtin_amdgcn_exp2f(acc[m][n][r]);
                    fs[m][r] += (col < c2) ? e : 0.0f;
                }
            }
    }
#pragma unroll
    for (int m = 0; m < 4; ++m)
#pragma unroll
        for (int r = 0; r < 4; ++r) {
            float f = fs[m][r];
#pragma unroll
            for (int msk = 1; msk < 16; msk <<= 1) f += __shfl_xor(f, msk);
            if (l15 == 0) {
                int rl = w * 64 + m * 16 + l4 * 4 + r;
                if (rl < c2) {
                    int grow = (rl < c) ? (int)glist[rl] : (int)glist[rl - c] + BQ;
                    grpsum[grow] = f;
                }
            }
        }
}

// ---- kernel 3: fused Gram + exp + row sums (NO mask work) ------------------
// grid 512 = 64 row-tiles x 8 chunks; 512 thr = 8 waves (4wr x 2wc).
// A frags hoisted; B double-buffered in LDS via global_load_lds; rolled loop.
__global__ __launch_bounds__(512, 2) void simloss_main(
        const ushort* __restrict__ obF, float* __restrict__ pf)
{
    __shared__ ushort bpan[2][16384];    // 2 x 32KB B tile (fragment order)
    __shared__ float  rred[2][128];      // row partials across wc

    const int tid  = threadIdx.x;
    const int lane = tid & 63;
    const int wid  = tid >> 6;
    const int wr   = wid >> 1;           // 0..3
    const int wc   = wid & 1;            // 0..1
    const int l15  = lane & 15;
    const int l4   = lane >> 4;

    // XCD swizzle: 512 blocks, ch == XCD -> each XCD reads one B chunk + A
    const int raw = blockIdx.x;
    const int bid = (raw & 7) * 64 + (raw >> 3);
    const int ch  = bid >> 6;            // 0..7
    const int rt  = bid & 63;            // 0..63
    const int rowbase = rt * 128;

    const bf16x8* F = reinterpret_cast<const bf16x8*>(obF);
    const char* gB = (const char*)obF + (size_t)ch * 262144;  // chunk's B cols
    char* lbase = (char*)&bpan[0][0];

    // prologue: stage buf0 (ct=0)
    {
        unsigned lb = (unsigned)__builtin_amdgcn_readfirstlane(wid * 1024);
        const char* g = gB + tid * 16;
#pragma unroll
        for (int r = 0; r < 4; ++r)
            gll(g + r * 8192, lbase + lb + r * 8192);
    }

    // A fragments for this block's 128 rows (wave wr: rows wr*32..wr*32+32)
    bf16x8 af[2][4];
#pragma unroll
    for (int m = 0; m < 2; ++m)
#pragma unroll
        for (int kk = 0; kk < 4; ++kk)
            af[m][kk] = F[((rt * 8 + wr * 2 + m) * 4 + kk) * 64 + lane];

    __syncthreads();   // vmcnt(0) drain -> buf0 ready

    float fs[2][4] = {};
    const unsigned bbase = (unsigned)(wc * 16384 + lane * 16);

    const char* gnext = gB + 32768 + tid * 16;   // next tile's global src
    unsigned stageLds = 32768 + wid * 1024;      // buf1 first

#pragma unroll 1
    for (int ct = 0; ct < NCT; ++ct) {
        // issue next tile's staging first; lands during this ct's compute
        if (ct < NCT - 1) {
            unsigned lb = (unsigned)__builtin_amdgcn_readfirstlane(stageLds);
#pragma unroll
            for (int r = 0; r < 4; ++r)
                gll(gnext + r * 8192, lbase + lb + r * 8192);
            gnext += 32768;
            stageLds ^= 32768;
        }

        const char* bufp = lbase + ((ct & 1) << 15);
        f32x4 acc[2][4] = {};
#pragma unroll
        for (int kk = 0; kk < 4; ++kk) {
            bf16x8 bf[4];
#pragma unroll
            for (int n = 0; n < 4; ++n)
                bf[n] = *reinterpret_cast<const bf16x8*>(
                    bufp + bbase + (unsigned)((n * 4 + kk) * 1024));
#pragma unroll
            for (int m = 0; m < 2; ++m)
#pragma unroll
                for (int n = 0; n < 4; ++n)
                    acc[m][n] = __builtin_amdgcn_mfma_f32_16x16x32_bf16(
                        af[m][kk], bf[n], acc[m][n], 0, 0, 0);
        }

        // epilogue: just exp2 + tree-sum (inputs pre-scaled; mask moved to group_k)
#pragma unroll
        for (int m = 0; m < 2; ++m)
#pragma unroll
            for (int r = 0; r < 4; ++r) {
                float e0 = __builtin_amdgcn_exp2f(acc[m][0][r]);
                float e1 = __builtin_amdgcn_exp2f(acc[m][1][r]);
                float e2 = __builtin_amdgcn_exp2f(acc[m][2][r]);
                float e3 = __builtin_amdgcn_exp2f(acc[m][3][r]);
                fs[m][r] += (e0 + e1) + (e2 + e3);
            }

        __syncthreads();   // buf consumed by all; next stage may overwrite
    }

    // reduce across the 16 column-lanes, combine wc halves via LDS
#pragma unroll
    for (int m = 0; m < 2; ++m)
#pragma unroll
        for (int r = 0; r < 4; ++r) {
            float f = fs[m][r];
#pragma unroll
            for (int msk = 1; msk < 16; msk <<= 1)
                f += __shfl_xor(f, msk);
            if (l15 == 0) {
                int rl = wr * 32 + m * 16 + l4 * 4 + r;
                rred[wc][rl] = f;
            }
        }
    __syncthreads();
    if (tid < 128)
        pf[ch * N2 + rowbase + tid] = rred[0][tid] + rred[1][tid];
}

// ---- kernel 4: per-row loss + block partial -------------------------------
__global__ __launch_bounds__(256) void row_loss_k(
        const float* __restrict__ pf, const float* __restrict__ grpsum,
        float* __restrict__ bpart)
{
    int row = blockIdx.x * 256 + threadIdx.x;
    float full = 0.f;
#pragma unroll
    for (int s = 0; s < NCHK; ++s)
        full += pf[s * N2 + row];
    float ng = full - grpsum[row];              // Ng = full - sum over excl set
    float o1 = full - 0.9f * ng;                // (1 - tau+) = 0.9
    float o2 = full + 818.1f * ng;              // n*tau+ - (1-tau+) = 819 - 0.9
    float li = (__builtin_amdgcn_logf(o2) - __builtin_amdgcn_logf(o1)) * 0.6931471805599453f;

#pragma unroll
    for (int m = 1; m < 64; m <<= 1) li += __shfl_xor(li, m);
    __shared__ float red[4];
    if ((threadIdx.x & 63) == 0) red[threadIdx.x >> 6] = li;
    __syncthreads();
    if (threadIdx.x == 0) bpart[blockIdx.x] = red[0] + red[1] + red[2] + red[3];
}

// ---- kernel 5: final scalar ----------------------------------------------
__global__ void final_k(const float* __restrict__ bpart, float* __restrict__ out)
{
    int l = threadIdx.x;
    float v = (l < 32) ? bpart[l] : 0.f;
#pragma unroll
    for (int m = 1; m < 32; m <<= 1) v += __shfl_xor(v, m);
    if (l == 0) out[0] = v / (float)N2;
}

extern "C" void kernel_launch(void* const* d_in, const int* in_sizes, int n_in,
                              void* d_out, int out_size, void* d_ws, size_t ws_size,
                              hipStream_t stream)
{
    const float* out1 = (const float*)d_in[0];
    const float* out2 = (const float*)d_in[1];
    // d_in[2] = out_m, unused by the loss math
    const int*   tgt  = (const int*)d_in[3];
    float* out = (float*)d_out;

    // ws: obF 2MB | pf 256KB | grpsum 32KB | bpart
    ushort* obF    = (ushort*)d_ws;
    float*  pf     = (float*)((char*)d_ws + (2u << 20));
    float*  grpsum = (float*)((char*)d_ws + (2u << 20) + 262144);
    float*  bpart  = (float*)((char*)d_ws + (2u << 20) + 262144 + 32768);

    convert_k<<<(N2 * DD / 8) / 256, 256, 0, stream>>>(out1, out2, obF);
    group_k<<<100, 256, 0, stream>>>(out1, out2, tgt, grpsum);
    simloss_main<<<512, 512, 0, stream>>>(obF, pf);
    row_loss_k<<<N2 / 256, 256, 0, stream>>>(pf, grpsum, bpart);
    final_k<<<1, 64, 0, stream>>>(bpart, out);
}

// Round 7
// 39.943 us; speedup vs baseline: 1.2475x; 1.2475x over previous
//
#include <hip/hip_runtime.h>
#include <hip/hip_bf16.h>

typedef __attribute__((ext_vector_type(8))) short bf16x8;
typedef __attribute__((ext_vector_type(4))) float f32x4;

constexpr int BQ  = 4096;          // batch per view
constexpr int DD  = 128;           // dim
constexpr int N2  = 2 * BQ;        // 8192
constexpr int NCHK = 8;            // column chunks (1024 cols each)
constexpr int NCT  = 8;            // 128-col tiles per chunk
// exp(s/T) = exp2(s * 2/ln2); pre-scale matrix by sqrt(2.8853900817779268)
constexpr float SQS = 1.6986433f;

static __device__ __forceinline__ ushort f2bf(float f) {
    unsigned u = __builtin_bit_cast(unsigned, f);
    u += 0x7FFFu + ((u >> 16) & 1u);     // round-to-nearest-even
    return (ushort)(u >> 16);
}

// ---- kernel 1: fp32 -> bf16 in MFMA-fragment order, plus mask keys --------
// obF layout: frag(group,kk) at index (group*4+kk)*64+lane, 8 bf16 per lane:
// a fragment load is F[base+lane] -> one fully contiguous 1KB load per wave.
__global__ __launch_bounds__(256) void convert_k(const float* __restrict__ a,
        const float* __restrict__ b, const int* __restrict__ tgt,
        ushort* __restrict__ obF, int* __restrict__ key)
{
    int t = blockIdx.x * 256 + threadIdx.x;          // 131072 threads
    int row = t >> 4, c8 = t & 15;
    const float* src = (row < BQ) ? (a + (size_t)row * DD + c8 * 8)
                                  : (b + (size_t)(row - BQ) * DD + c8 * 8);
    float4 v0 = reinterpret_cast<const float4*>(src)[0];
    float4 v1 = reinterpret_cast<const float4*>(src)[1];
    bf16x8 res;
    res[0] = (short)f2bf(v0.x * SQS); res[1] = (short)f2bf(v0.y * SQS);
    res[2] = (short)f2bf(v0.z * SQS); res[3] = (short)f2bf(v0.w * SQS);
    res[4] = (short)f2bf(v1.x * SQS); res[5] = (short)f2bf(v1.y * SQS);
    res[6] = (short)f2bf(v1.z * SQS); res[7] = (short)f2bf(v1.w * SQS);
    int frag = ((row >> 4) * 4 + (c8 >> 2)) * 64 + (c8 & 3) * 16 + (row & 15);
    *reinterpret_cast<bf16x8*>(obF + (size_t)frag * 8) = res;

    if (t < N2) {
        // excl(i,j) == (key[i]==key[j]) covers BOTH the pair mask and the
        // target mask (rowmod==colmod implies identical target).
        int tv = tgt[t & (BQ - 1)];
        key[t] = (tv == -1) ? (0x40000000 + (t & (BQ - 1))) : tv;
    }
}

// ---- kernel 2: fused Gram + exp + mask + row sums --------------------------
// grid 512 = 64 row-tiles x 8 chunks; 512 thr = 8 waves (4wr x 2wc).
// NO LDS staging, NO barriers in the hot loop: B fragments are read straight
// from L2 (2MB matrix; each XCD touches only its 256KB chunk via ch==XCD
// swizzle). Every fragment load is a contiguous wave-wide 1KB transaction.
__global__ __launch_bounds__(512, 4) void simloss_main(
        const ushort* __restrict__ obF, const int* __restrict__ key,
        float* __restrict__ pf, float* __restrict__ png)
{
    __shared__ float rred[2][128][2];    // row partials across wc

    const int tid  = threadIdx.x;
    const int lane = tid & 63;
    const int wid  = tid >> 6;
    const int wr   = wid >> 1;           // 0..3
    const int wc   = wid & 1;            // 0..1
    const int l15  = lane & 15;
    const int l4   = lane >> 4;

    // XCD swizzle: 512 blocks, ch == XCD -> each XCD reads one B chunk + A
    const int raw = blockIdx.x;
    const int bid = (raw & 7) * 64 + (raw >> 3);
    const int ch  = bid >> 6;            // 0..7
    const int rt  = bid & 63;            // 0..63
    const int rowbase = rt * 128;

    const bf16x8* F = reinterpret_cast<const bf16x8*>(obF);

    // A fragments for this block's 128 rows (wave wr: rows wr*32..wr*32+32)
    bf16x8 af[2][4];
#pragma unroll
    for (int m = 0; m < 2; ++m)
#pragma unroll
        for (int kk = 0; kk < 4; ++kk)
            af[m][kk] = F[((rt * 8 + wr * 2 + m) * 4 + kk) * 64 + lane];

    int rk[2][4];
#pragma unroll
    for (int m = 0; m < 2; ++m)
#pragma unroll
        for (int r = 0; r < 4; ++r)
            rk[m][r] = key[rowbase + wr * 32 + m * 16 + l4 * 4 + r];

    float fs[2][4] = {}, ns[2][4] = {};

    // wave's B base: col group gc0 = ch*64 + wc*4; frag (gc0+ct*8+n, kk)
    const bf16x8* Bp = F + (size_t)(ch * 64 + wc * 4) * 4 * 64 + lane;
    const int*    kp = key + ch * 1024 + wc * 64 + l15;

#pragma unroll 1
    for (int ct = 0; ct < NCT; ++ct) {
        const bf16x8* Bct = Bp + ct * 2048;      // += ct*8 col-groups
        int ck[4];
#pragma unroll
        for (int n = 0; n < 4; ++n)
            ck[n] = kp[ct * 128 + n * 16];

        f32x4 acc[2][4] = {};
#pragma unroll
        for (int kk = 0; kk < 4; ++kk) {
            bf16x8 bf[4];
#pragma unroll
            for (int n = 0; n < 4; ++n)
                bf[n] = Bct[(n * 4 + kk) * 64];
#pragma unroll
            for (int m = 0; m < 2; ++m)
#pragma unroll
                for (int n = 0; n < 4; ++n)
                    acc[m][n] = __builtin_amdgcn_mfma_f32_16x16x32_bf16(
                        af[m][kk], bf[n], acc[m][n], 0, 0, 0);
        }

        // epilogue: exp2 directly (inputs pre-scaled); single-compare mask
#pragma unroll
        for (int m = 0; m < 2; ++m)
#pragma unroll
            for (int n = 0; n < 4; ++n)
#pragma unroll
                for (int r = 0; r < 4; ++r) {
                    float e = __builtin_amdgcn_exp2f(acc[m][n][r]);
                    fs[m][r] += e;
                    ns[m][r] += (rk[m][r] == ck[n]) ? 0.0f : e;
                }
    }

    // reduce across the 16 column-lanes, combine wc halves via LDS
#pragma unroll
    for (int m = 0; m < 2; ++m)
#pragma unroll
        for (int r = 0; r < 4; ++r) {
            float f = fs[m][r], g = ns[m][r];
#pragma unroll
            for (int msk = 1; msk < 16; msk <<= 1) {
                f += __shfl_xor(f, msk);
                g += __shfl_xor(g, msk);
            }
            if (l15 == 0) {
                int rl = wr * 32 + m * 16 + l4 * 4 + r;
                rred[wc][rl][0] = f;
                rred[wc][rl][1] = g;
            }
        }
    __syncthreads();
    if (tid < 128) {
        float f = rred[0][tid][0] + rred[1][tid][0];
        float g = rred[0][tid][1] + rred[1][tid][1];
        pf [ch * N2 + rowbase + tid] = f;
        png[ch * N2 + rowbase + tid] = g;
    }
}

// ---- kernel 3: per-row loss + block partial -------------------------------
__global__ __launch_bounds__(256) void row_loss_k(
        const float* __restrict__ pf, const float* __restrict__ png,
        float* __restrict__ bpart)
{
    int row = blockIdx.x * 256 + threadIdx.x;
    float full = 0.f, ng = 0.f;
#pragma unroll
    for (int s = 0; s < NCHK; ++s) {
        full += pf[s * N2 + row];
        ng   += png[s * N2 + row];
    }
    float o1 = full - 0.9f * ng;                // (1 - tau+) = 0.9
    float o2 = full + 818.1f * ng;              // n*tau+ - (1-tau+) = 819 - 0.9
    float li = (__builtin_amdgcn_logf(o2) - __builtin_amdgcn_logf(o1)) * 0.6931471805599453f;

#pragma unroll
    for (int m = 1; m < 64; m <<= 1) li += __shfl_xor(li, m);
    __shared__ float red[4];
    if ((threadIdx.x & 63) == 0) red[threadIdx.x >> 6] = li;
    __syncthreads();
    if (threadIdx.x == 0) bpart[blockIdx.x] = red[0] + red[1] + red[2] + red[3];
}

// ---- kernel 4: final scalar ----------------------------------------------
__global__ void final_k(const float* __restrict__ bpart, float* __restrict__ out)
{
    int l = threadIdx.x;
    float v = (l < 32) ? bpart[l] : 0.f;
#pragma unroll
    for (int m = 1; m < 32; m <<= 1) v += __shfl_xor(v, m);
    if (l == 0) out[0] = v / (float)N2;
}

extern "C" void kernel_launch(void* const* d_in, const int* in_sizes, int n_in,
                              void* d_out, int out_size, void* d_ws, size_t ws_size,
                              hipStream_t stream)
{
    const float* out1 = (const float*)d_in[0];
    const float* out2 = (const float*)d_in[1];
    // d_in[2] = out_m, unused by the loss math
    const int*   tgt  = (const int*)d_in[3];
    float* out = (float*)d_out;

    // ws: obF 2MB | pf 256KB | png 256KB | key 32KB | bpart
    ushort* obF  = (ushort*)d_ws;
    float*  pf   = (float*)((char*)d_ws + (2u << 20));
    float*  png  = (float*)((char*)d_ws + (2u << 20) + 262144);
    int*    key  = (int*)  ((char*)d_ws + (2u << 20) + 524288);
    float*  bpart= (float*)((char*)d_ws + (2u << 20) + 524288 + 32768);

    convert_k<<<(N2 * DD / 8) / 256, 256, 0, stream>>>(out1, out2, tgt, obF, key);
    simloss_main<<<512, 512, 0, stream>>>(obF, key, pf, png);
    row_loss_k<<<N2 / 256, 256, 0, stream>>>(pf, png, bpart);
    final_k<<<1, 64, 0, stream>>>(bpart, out);
}

// Round 8
// 38.361 us; speedup vs baseline: 1.2989x; 1.0413x over previous
//
#include <hip/hip_runtime.h>
#include <hip/hip_bf16.h>

typedef __attribute__((ext_vector_type(4))) float f32x4;

constexpr int BQ  = 4096;          // batch per view
constexpr int DD  = 128;           // dim
constexpr int N2  = 2 * BQ;        // 8192
constexpr int NCHK = 8;            // column chunks (1024 cols each)
constexpr int NCT  = 16;           // 64-col tiles per chunk
// exp(s/T) = exp2(s * 2/ln2); pre-scale matrix by sqrt(2.8853900817779268)
constexpr float SQS = 1.6986433f;

// ---- kernel 1: fp32 -> fp8(e4m3) in MFMA-fragment order, plus mask keys ----
// obF layout: frag(group,kk) = 64 lanes x 8 bytes at index (group*4+kk)*64+lane
// (long units). Lane l: row = group*16 + (l&15), k = kk*32 + (l>>4)*8 + j.
__global__ __launch_bounds__(256) void convert_k(const float* __restrict__ a,
        const float* __restrict__ b, const int* __restrict__ tgt,
        long* __restrict__ obF, int* __restrict__ key)
{
    int t = blockIdx.x * 256 + threadIdx.x;          // 131072 threads
    int row = t >> 4, c8 = t & 15;
    const float* src = (row < BQ) ? (a + (size_t)row * DD + c8 * 8)
                                  : (b + (size_t)(row - BQ) * DD + c8 * 8);
    float4 v0 = reinterpret_cast<const float4*>(src)[0];
    float4 v1 = reinterpret_cast<const float4*>(src)[1];
    int lo = __builtin_amdgcn_cvt_pk_fp8_f32(v0.x * SQS, v0.y * SQS, 0, false);
    lo     = __builtin_amdgcn_cvt_pk_fp8_f32(v0.z * SQS, v0.w * SQS, lo, true);
    int hi = __builtin_amdgcn_cvt_pk_fp8_f32(v1.x * SQS, v1.y * SQS, 0, false);
    hi     = __builtin_amdgcn_cvt_pk_fp8_f32(v1.z * SQS, v1.w * SQS, hi, true);
    long v = (((long)hi) << 32) | (unsigned)lo;
    int frag = ((row >> 4) * 4 + (c8 >> 2)) * 64 + (c8 & 3) * 16 + (row & 15);
    obF[frag] = v;

    if (t < N2) {
        // excl(i,j) == (key[i]==key[j]) covers BOTH the pair mask and the
        // target mask (rowmod==colmod implies identical target).
        int tv = tgt[t & (BQ - 1)];
        key[t] = (tv == -1) ? (0x40000000 + (t & (BQ - 1))) : tv;
    }
}

// ---- kernel 2: fused fp8 Gram + exp + mask + row sums ----------------------
// grid 512 = 64 row-tiles x 8 chunks; 256 thr = 4 waves (2wr x 2wc).
// Wave tile 64 rows x 32 cols per ct -> B traffic 2 B/elem. No barriers in
// the hot loop; B read straight from L2 (1MB fp8 matrix, ch==XCD swizzle)
// with a manual 2-deep ping-pong register prefetch.
__global__ __launch_bounds__(256, 3) void simloss_main(
        const long* __restrict__ F8, const int* __restrict__ key,
        float* __restrict__ pf, float* __restrict__ png)
{
    __shared__ float rred[2][128][2];    // row partials across wc

    const int tid  = threadIdx.x;
    const int lane = tid & 63;
    const int wid  = tid >> 6;
    const int wr   = wid >> 1;           // 0..1 (64-row half)
    const int wc   = wid & 1;            // 0..1 (32-col half)
    const int l15  = lane & 15;
    const int l4   = lane >> 4;

    // XCD swizzle: 512 blocks, ch == XCD -> each XCD reads one B chunk + A
    const int raw = blockIdx.x;
    const int bid = (raw & 7) * 64 + (raw >> 3);
    const int ch  = bid >> 6;            // 0..7
    const int rt  = bid & 63;            // 0..63
    const int rowbase = rt * 128;

    // A fragments: wave wr owns rows wr*64..wr*64+63 = groups rt*8+wr*4+m
    long af[4][4];
#pragma unroll
    for (int m = 0; m < 4; ++m)
#pragma unroll
        for (int kk = 0; kk < 4; ++kk)
            af[m][kk] = F8[((rt * 8 + wr * 4 + m) * 4 + kk) * 64 + lane];

    int rk[4][4];
#pragma unroll
    for (int m = 0; m < 4; ++m)
#pragma unroll
        for (int r = 0; r < 4; ++r)
            rk[m][r] = key[rowbase + wr * 64 + m * 16 + l4 * 4 + r];

    float fs[4][4] = {}, ns[4][4] = {};

    // B base for this wave: frag index (ch*256 + ct*16 + wc*8 + n*4 + kk)*64+lane
    const long* Bw = F8 + (size_t)(ch * 256 + wc * 8) * 64 + lane;
    const int*  kp = key + ch * 1024 + wc * 32 + l15;

    auto loadB = [&](long bx[8], int ct) {
        const long* p = Bw + ct * 1024;
#pragma unroll
        for (int q = 0; q < 8; ++q) bx[q] = p[q * 64];
    };
    auto compute = [&](const long bx[8], int ct) {
        int ck0 = kp[ct * 64];
        int ck1 = kp[ct * 64 + 16];
        f32x4 acc[4][2] = {};
#pragma unroll
        for (int kk = 0; kk < 4; ++kk)
#pragma unroll
            for (int m = 0; m < 4; ++m) {
                acc[m][0] = __builtin_amdgcn_mfma_f32_16x16x32_fp8_fp8(
                    af[m][kk], bx[kk], acc[m][0], 0, 0, 0);
                acc[m][1] = __builtin_amdgcn_mfma_f32_16x16x32_fp8_fp8(
                    af[m][kk], bx[4 + kk], acc[m][1], 0, 0, 0);
            }
        // epilogue: exp2 directly (inputs pre-scaled); single-compare mask
#pragma unroll
        for (int m = 0; m < 4; ++m)
#pragma unroll
            for (int r = 0; r < 4; ++r) {
                float e0 = __builtin_amdgcn_exp2f(acc[m][0][r]);
                float e1 = __builtin_amdgcn_exp2f(acc[m][1][r]);
                fs[m][r] += e0 + e1;
                ns[m][r] += ((rk[m][r] == ck0) ? 0.0f : e0)
                          + ((rk[m][r] == ck1) ? 0.0f : e1);
            }
    };

    long bA[8], bB[8];
    loadB(bA, 0);
#pragma unroll 1
    for (int ct = 0; ct < NCT; ct += 2) {
        loadB(bB, ct + 1);            // prefetch next tile during compute
        compute(bA, ct);
        if (ct + 2 < NCT) loadB(bA, ct + 2);
        compute(bB, ct + 1);
    }

    // reduce across the 16 column-lanes, combine wc halves via LDS
#pragma unroll
    for (int m = 0; m < 4; ++m)
#pragma unroll
        for (int r = 0; r < 4; ++r) {
            float f = fs[m][r], g = ns[m][r];
#pragma unroll
            for (int msk = 1; msk < 16; msk <<= 1) {
                f += __shfl_xor(f, msk);
                g += __shfl_xor(g, msk);
            }
            if (l15 == 0) {
                int rl = wr * 64 + m * 16 + l4 * 4 + r;
                rred[wc][rl][0] = f;
                rred[wc][rl][1] = g;
            }
        }
    __syncthreads();
    if (tid < 128) {
        pf [ch * N2 + rowbase + tid] = rred[0][tid][0] + rred[1][tid][0];
        png[ch * N2 + rowbase + tid] = rred[0][tid][1] + rred[1][tid][1];
    }
}

// ---- kernel 3: per-row loss + block partial -------------------------------
__global__ __launch_bounds__(256) void row_loss_k(
        const float* __restrict__ pf, const float* __restrict__ png,
        float* __restrict__ bpart)
{
    int row = blockIdx.x * 256 + threadIdx.x;
    float full = 0.f, ng = 0.f;
#pragma unroll
    for (int s = 0; s < NCHK; ++s) {
        full += pf[s * N2 + row];
        ng   += png[s * N2 + row];
    }
    float o1 = full - 0.9f * ng;                // (1 - tau+) = 0.9
    float o2 = full + 818.1f * ng;              // n*tau+ - (1-tau+) = 819 - 0.9
    float li = (__builtin_amdgcn_logf(o2) - __builtin_amdgcn_logf(o1)) * 0.6931471805599453f;

#pragma unroll
    for (int m = 1; m < 64; m <<= 1) li += __shfl_xor(li, m);
    __shared__ float red[4];
    if ((threadIdx.x & 63) == 0) red[threadIdx.x >> 6] = li;
    __syncthreads();
    if (threadIdx.x == 0) bpart[blockIdx.x] = red[0] + red[1] + red[2] + red[3];
}

// ---- kernel 4: final scalar ----------------------------------------------
__global__ void final_k(const float* __restrict__ bpart, float* __restrict__ out)
{
    int l = threadIdx.x;
    float v = (l < 32) ? bpart[l] : 0.f;
#pragma unroll
    for (int m = 1; m < 32; m <<= 1) v += __shfl_xor(v, m);
    if (l == 0) out[0] = v / (float)N2;
}

extern "C" void kernel_launch(void* const* d_in, const int* in_sizes, int n_in,
                              void* d_out, int out_size, void* d_ws, size_t ws_size,
                              hipStream_t stream)
{
    const float* out1 = (const float*)d_in[0];
    const float* out2 = (const float*)d_in[1];
    // d_in[2] = out_m, unused by the loss math
    const int*   tgt  = (const int*)d_in[3];
    float* out = (float*)d_out;

    // ws: obF8 1MB | pf 256KB | png 256KB | key 32KB | bpart
    long*   obF  = (long*)d_ws;
    float*  pf   = (float*)((char*)d_ws + (1u << 20));
    float*  png  = (float*)((char*)d_ws + (1u << 20) + 262144);
    int*    key  = (int*)  ((char*)d_ws + (1u << 20) + 524288);
    float*  bpart= (float*)((char*)d_ws + (1u << 20) + 524288 + 32768);

    convert_k<<<512, 256, 0, stream>>>(out1, out2, tgt, obF, key);
    simloss_main<<<512, 256, 0, stream>>>(obF, key, pf, png);
    row_loss_k<<<N2 / 256, 256, 0, stream>>>(pf, png, bpart);
    final_k<<<1, 64, 0, stream>>>(bpart, out);
}